// Round 1
// baseline (324.414 us; speedup 1.0000x reference)
//
#include <hip/hip_runtime.h>
#include <hip/hip_bf16.h>

#define BATCH 16384
#define HID   1024
#define EMBD  512
#define NOPS  8
#define MAXT  136   // max tile slots: sum ceil(cnt_e/128) <= 135
#define CNTS  16    // cnt stride in ints (64 B) — one cache line per expert

typedef __attribute__((ext_vector_type(8))) short bf16x8;
typedef __attribute__((ext_vector_type(4))) float f32x4;

__device__ __forceinline__ unsigned short f2bf(float f) {
  unsigned int u = __float_as_uint(f);
  u += 0x7FFF + ((u >> 16) & 1);
  return (unsigned short)(u >> 16);
}

__device__ __forceinline__ unsigned int pk2(float a, float b) {
  __hip_bfloat162 t = __float22bfloat162_rn(make_float2(a, b));
  return *(unsigned int*)(&t);
}

__device__ __forceinline__ void lds_load16(void* lds, const void* g) {
  __builtin_amdgcn_global_load_lds(
      (const __attribute__((address_space(1))) unsigned int*)g,
      (__attribute__((address_space(3))) unsigned int*)lds, 16, 0, 0);
}

// XCD-locality decode: linear blocks round-robin across 8 XCDs, so bid&7 is
// the XCD. All 8 nx-blocks of a g land on one XCD (A-slab L2 reuse), and each
// XCD covers contiguous g-range [17c, 17c+17) ~= one expert (W-slab in L2).
__device__ __forceinline__ void decode_bid(int bid, int& g, int& nx) {
  g = 17 * (bid & 7) + (bid >> 6);
  nx = (bid >> 3) & 7;
}

// LDS-free weight transpose tile, fq-major slab layout:
//   slab[kq][n][kk] bf16 (kq=k/8 in 0..3, n in 0..127, kk=k%8)
//   value = W[ks*32 + kq*8 + kk][nx*128 + n]
// Fragment ds_read (fq*128+row)*16B then hits every bank-quad exactly once
// per aligned 8-lane group -> conflict-free (old row-major [128][32] was
// 8-way aliased: 5.0M SQ_LDS_BANK_CONFLICT cycles measured).
__device__ __forceinline__ void w_prep_tile(const float* __restrict__ W,
                                            short* __restrict__ Wp,
                                            int ks, int nx, int tid) {
  int n = tid & 127, kh = tid >> 7;           // kh: low/high 16 of the 32-k tile
  const float* src = W + (size_t)(ks * 32 + kh * 16) * 1024 + nx * 128 + n;
  float v[16];
#pragma unroll
  for (int kk = 0; kk < 16; ++kk) v[kk] = src[(size_t)kk * 1024];
  uint4 a, b;
  a.x = pk2(v[0], v[1]);  a.y = pk2(v[2], v[3]);
  a.z = pk2(v[4], v[5]);  a.w = pk2(v[6], v[7]);
  b.x = pk2(v[8], v[9]);  b.y = pk2(v[10], v[11]);
  b.z = pk2(v[12], v[13]); b.w = pk2(v[14], v[15]);
  uint4* dst = (uint4*)Wp;
  dst[(2 * kh) * 128 + n]     = a;            // kq = 2*kh   (k 0..7 of this half)
  dst[(2 * kh + 1) * 128 + n] = b;            // kq = 2*kh+1 (k 8..15)
}

// ---------------- phase 0: bucket (64) + ce (128) + W1 prep (2048) -----------
// W1 prep rides here (deadline = gemm1), eliminating the old prep_k pass.
// ce[e][n] = b1[e][n] + sum_k emb[e][k] * W1[e][1024+k][n] — embedding half of
// GEMM1 collapses to a per-(expert,n) constant, cutting GEMM1 K 1536 -> 1024.
__global__ void bucket_ce_k(const int* __restrict__ ops, int* __restrict__ cnt,
                            int* __restrict__ idx, const float* __restrict__ W1,
                            const float* __restrict__ emb,
                            const float* __restrict__ b1, float* __restrict__ ce,
                            short* __restrict__ W1p) {
  int bid = blockIdx.x;
  int tid = threadIdx.x;
  if (bid >= 192) {
    // ---- W1 path: 8 e * 8 nx * 32 ks (first 1024 rows only) ----
    int b = bid - 192;
    int e = b / 256; int rr = b % 256; int nx = rr / 32, ks = rr % 32;
    w_prep_tile(W1 + (size_t)e * 1536 * 1024,
                W1p + ((size_t)(e * 8 + nx) * 32 + ks) * 4096, ks, nx, tid);
    return;
  }
  if (bid >= 64) {
    // ---- ce path ----
    int cb = bid - 64;
    int e = cb >> 4, kp = cb & 15;
    int n = tid * 4;
    const float* Wc = W1 + (size_t)e * 1536 * 1024 + (size_t)(1024 + kp * 32) * 1024 + n;
    const float* ee = emb + e * EMBD + kp * 32;
    float4 a = make_float4(0.f, 0.f, 0.f, 0.f);
#pragma unroll
    for (int kk = 0; kk < 32; ++kk) {
      float s = ee[kk];
      float4 r = *(const float4*)(Wc + (size_t)kk * 1024);
      a.x += s * r.x; a.y += s * r.y; a.z += s * r.z; a.w += s * r.w;
    }
    if (kp == 0) {
      float4 b = *(const float4*)(b1 + e * HID + n);
      a.x += b.x; a.y += b.y; a.z += b.z; a.w += b.w;
    }
    float* d = ce + e * HID + n;
    atomicAdd(d + 0, a.x); atomicAdd(d + 1, a.y);
    atomicAdd(d + 2, a.z); atomicAdd(d + 3, a.w);
    return;
  }
  // ---- bucket path (block-aggregated atomics) ----
  __shared__ int wcnt[4][NOPS];
  __shared__ int wbase[4][NOPS];
  int lane = tid & 63, w = tid >> 6;
  int t = bid * 256 + tid;
  int op = ops[t];
  unsigned long long msave = 0;
#pragma unroll
  for (int o = 0; o < NOPS; ++o) {
    unsigned long long mm = __ballot(op == o);
    if (op == o) msave = mm;
    if (lane == o) wcnt[w][o] = __popcll(mm);
  }
  __syncthreads();
  if (tid < NOPS) {
    int c0 = wcnt[0][tid], c1 = wcnt[1][tid], c2 = wcnt[2][tid], c3 = wcnt[3][tid];
    int base = atomicAdd(&cnt[tid * CNTS], c0 + c1 + c2 + c3);
    wbase[0][tid] = base;
    wbase[1][tid] = base + c0;
    wbase[2][tid] = base + c0 + c1;
    wbase[3][tid] = base + c0 + c1 + c2;
  }
  __syncthreads();
  int pre = __popcll(msave & ((1ull << lane) - 1ull));
  idx[op * BATCH + wbase[w][op] + pre] = t;
}

// build tile descriptors + pad index lists to tile multiples (parallel fill)
__global__ void schedule_k(const int* __restrict__ cnt, int* __restrict__ desc,
                           int* __restrict__ ntp, int* __restrict__ idx) {
  __shared__ int base[NOPS + 1];
  int tid = threadIdx.x;
  if (tid == 0) {
    int n = 0;
    for (int e = 0; e < NOPS; ++e) { base[e] = n; n += (cnt[e * CNTS] + 127) >> 7; }
    base[NOPS] = n;
    *ntp = n;
  }
  __syncthreads();
  for (int e = 0; e < NOPS; ++e) {
    int b0 = base[e], nt = base[e + 1] - b0;
    for (int t = tid; t < nt; t += 256) {
      desc[2 * (b0 + t)] = e;
      desc[2 * (b0 + t) + 1] = t * 128;
    }
  }
  for (int e = 0; e < NOPS; ++e) {
    int c = cnt[e * CNTS];
    int cp = (c + 127) & ~127;
    for (int p = c + tid; p < cp; p += 256) idx[e * BATCH + p] = 0;
  }
}

// ---------------- phase 1: GEMM1 fused A-gather (1088) + W2 prep (2048) ------
// h = relu(x_tile @ W1[e][:1024] + ce[e]); K = 1024 (32 iters).
// A is gathered from x in-kernel: per ks each thread loads 16 f32 of its token
// row, cvt_pk->bf16, ds_write_b128 (fq-major). Next-ks loads are issued AFTER
// barrier1 so their latency hides under the MFMA phase (drained at barrier2).
// B (W1p) keeps the global_load_lds fast path. W2 prep rides co-resident.
__global__ __launch_bounds__(256) void gemm1_w2_k(
    const float* __restrict__ x, const int* __restrict__ idx,
    const float* __restrict__ ce, const short* __restrict__ W1p,
    unsigned short* __restrict__ hp, const int* __restrict__ desc,
    const int* __restrict__ ntp, const float* __restrict__ W2,
    short* __restrict__ W2p) {
  int bid = blockIdx.x;
  int tid = threadIdx.x;
  if (bid >= 8 * MAXT) {
    // ---- W2 path: 8 e * 8 nx * 32 ks ----
    int b = bid - 8 * MAXT;
    int e = b / 256; int rr = b % 256; int nx = rr / 32, ks = rr % 32;
    w_prep_tile(W2 + (size_t)e * 1024 * 1024,
                W2p + ((size_t)(e * 8 + nx) * 32 + ks) * 4096, ks, nx, tid);
    return;
  }
  int g, nx;
  decode_bid(bid, g, nx);
  if (g >= *ntp) return;
  int e = desc[2 * g], rs = desc[2 * g + 1];

  __shared__ __align__(16) char smem[16384];
  __shared__ int toks[128];
  short* lA = (short*)smem;
  short* lB = (short*)(smem + 8192);

  int lane = tid & 63, w = tid >> 6;
  int wm = w >> 1, wn = w & 1;
  int fr = lane & 15, fq = lane >> 4;
  int ar = tid >> 1, ah = tid & 1;   // gather role: token row ar, half ah

  if (tid < 128) toks[tid] = idx[e * BATCH + rs + tid];
  __syncthreads();
  const float* xrow = x + (size_t)toks[ar] * HID + ah * 16;
  const char* Bsrc = (const char*)W1p + (size_t)(e * 8 + nx) * 32 * 8192;

  f32x4 acc[4][4] = {};
  // prologue: f32 for ks=0
  float4 fa0 = ((const float4*)xrow)[0];
  float4 fa1 = ((const float4*)xrow)[1];
  float4 fa2 = ((const float4*)xrow)[2];
  float4 fa3 = ((const float4*)xrow)[3];

  for (int ks = 0; ks < 32; ++ks) {
    // issue B staging first (async), then convert+write A
    const char* bs = Bsrc + ks * 8192;
    lds_load16(smem + 8192 + w * 1024, bs + w * 1024 + lane * 16);
    lds_load16(smem + 12288 + w * 1024, bs + 4096 + w * 1024 + lane * 16);
    uint4 p0 = make_uint4(pk2(fa0.x, fa0.y), pk2(fa0.z, fa0.w),
                          pk2(fa1.x, fa1.y), pk2(fa1.z, fa1.w));
    uint4 p1 = make_uint4(pk2(fa2.x, fa2.y), pk2(fa2.z, fa2.w),
                          pk2(fa3.x, fa3.y), pk2(fa3.z, fa3.w));
    // fq-major: value[kq][row][kk]; this thread covers kq=2ah (p0), 2ah+1 (p1)
    *(uint4*)&lA[((2 * ah) * 128 + ar) * 8] = p0;
    *(uint4*)&lA[((2 * ah + 1) * 128 + ar) * 8] = p1;
    __syncthreads();
    // prefetch next ks A (f32) — hides under MFMA, drains at barrier2
    if (ks < 31) {
      const float4* src = (const float4*)(xrow + (ks + 1) * 32);
      fa0 = src[0]; fa1 = src[1]; fa2 = src[2]; fa3 = src[3];
    }
    bf16x8 af[4], bfr[4];
#pragma unroll
    for (int i = 0; i < 4; ++i)
      af[i] = *(const bf16x8*)&lA[(fq * 128 + wm * 64 + i * 16 + fr) * 8];
#pragma unroll
    for (int j = 0; j < 4; ++j)
      bfr[j] = *(const bf16x8*)&lB[(fq * 128 + wn * 64 + j * 16 + fr) * 8];
#pragma unroll
    for (int i = 0; i < 4; ++i)
#pragma unroll
      for (int j = 0; j < 4; ++j)
        acc[i][j] = __builtin_amdgcn_mfma_f32_16x16x32_bf16(af[i], bfr[j], acc[i][j], 0, 0, 0);
    __syncthreads();
  }

  // epilogue: +ce (bias incl. embedding term) + relu + bf16, coalesced via LDS.
  // hp layout (fq-major): [g][ks2(32)][kq(4)][128 r][8 k] — gemm2 staging is a
  // linear 8 KB slab copy. LDS round-trip read gets a 1-bit XOR swizzle to
  // spread its former 16-way bank aliasing.
  float bias[4];
#pragma unroll
  for (int j = 0; j < 4; ++j)
    bias[j] = ce[e * HID + nx * 128 + wn * 64 + j * 16 + fr];

  int lr = lane >> 2;
#pragma unroll
  for (int i = 0; i < 4; ++i) {
    __syncthreads();
#pragma unroll
    for (int j = 0; j < 4; ++j)
#pragma unroll
      for (int rg = 0; rg < 4; ++rg) {
        float v = acc[i][j][rg] + bias[j];
        v = v > 0.f ? v : 0.f;
        int row16 = fq * 4 + rg;
        int off = w * 2048 + row16 * 128 + (j * 16 + fr) * 2;
        off ^= (row16 & 1) << 6;
        *(unsigned short*)(smem + off) = f2bf(v);
      }
    __syncthreads();
    int R = wm * 64 + i * 16 + lr;
#pragma unroll
    for (int s = 0; s < 2; ++s) {
      int ch = (lane & 3) + s * 4;
      int off = w * 2048 + lr * 128 + ch * 16;
      off ^= (lr & 1) << 6;
      uint4 val = *(const uint4*)(smem + off);
      int ks2 = nx * 4 + wn * 2 + (ch >> 2);
      int kq = ch & 3;
      *(uint4*)(hp + (((size_t)(g * 32 + ks2) * 4 + kq) * 128 + R) * 8) = val;
    }
  }
}

// ---------------- phase 2: GEMM2  out[tok] = relu(h @ W2[e] + b2[e]) ---------
__global__ __launch_bounds__(256) void gemm2_k(
    const unsigned short* __restrict__ hp, const float* __restrict__ b2,
    const short* __restrict__ W2p, float* __restrict__ out,
    const int* __restrict__ idx, const int* __restrict__ cnt,
    const int* __restrict__ desc, const int* __restrict__ ntp) {
  int g, nx;
  decode_bid(blockIdx.x, g, nx);
  if (g >= *ntp) return;
  int e = desc[2 * g], rs = desc[2 * g + 1];
  int ce2 = cnt[e * CNTS];

  __shared__ __align__(16) char smem[16384];
  __shared__ int toks[128];
  short* lA = (short*)smem;
  short* lB = (short*)(smem + 8192);

  int tid = threadIdx.x, lane = tid & 63, w = tid >> 6;
  int wm = w >> 1, wn = w & 1;
  int fr = lane & 15, fq = lane >> 4;

  if (tid < 128) toks[tid] = idx[e * BATCH + rs + tid];

  const char* Asrc = (const char*)hp + (size_t)g * 32 * 8192;
  const char* Bsrc = (const char*)W2p + (size_t)(e * 8 + nx) * 32 * 8192;

  f32x4 acc[4][4] = {};

  for (int ks = 0; ks < 32; ++ks) {
    const char* as = Asrc + ks * 8192;
    const char* bs = Bsrc + ks * 8192;
    lds_load16(smem + w * 1024, as + w * 1024 + lane * 16);
    lds_load16(smem + 4096 + w * 1024, as + 4096 + w * 1024 + lane * 16);
    lds_load16(smem + 8192 + w * 1024, bs + w * 1024 + lane * 16);
    lds_load16(smem + 12288 + w * 1024, bs + 4096 + w * 1024 + lane * 16);
    __syncthreads();

    bf16x8 af[4], bfr[4];
#pragma unroll
    for (int i = 0; i < 4; ++i)
      af[i] = *(const bf16x8*)&lA[(fq * 128 + wm * 64 + i * 16 + fr) * 8];
#pragma unroll
    for (int j = 0; j < 4; ++j)
      bfr[j] = *(const bf16x8*)&lB[(fq * 128 + wn * 64 + j * 16 + fr) * 8];
#pragma unroll
    for (int i = 0; i < 4; ++i)
#pragma unroll
      for (int j = 0; j < 4; ++j)
        acc[i][j] = __builtin_amdgcn_mfma_f32_16x16x32_bf16(af[i], bfr[j], acc[i][j], 0, 0, 0);
    __syncthreads();
  }

  // epilogue: bias + relu + scatter to out rows, coalesced via LDS round-trip.
  float bias[4];
#pragma unroll
  for (int j = 0; j < 4; ++j)
    bias[j] = b2[e * HID + nx * 128 + wn * 64 + j * 16 + fr];

  int lr = lane >> 2;
#pragma unroll
  for (int i = 0; i < 4; ++i) {
    __syncthreads();
#pragma unroll
    for (int j = 0; j < 4; ++j)
#pragma unroll
      for (int rg = 0; rg < 4; ++rg) {
        float v = acc[i][j][rg] + bias[j];
        int row16 = fq * 4 + rg;
        int off = w * 4096 + row16 * 256 + (j * 16 + fr) * 4;
        off ^= (row16 & 1) << 6;
        *(float*)(smem + off) = v > 0.f ? v : 0.f;
      }
    __syncthreads();
    int R = wm * 64 + i * 16 + lr;
    if (R < ce2 - rs) {
      float* orow = out + (size_t)toks[R] * HID + nx * 128 + wn * 64;
#pragma unroll
      for (int s = 0; s < 4; ++s) {
        int ch = (lane & 3) + s * 4;
        int off = w * 4096 + lr * 256 + ch * 16;
        off ^= (lr & 1) << 6;
        *(float4*)(orow + ch * 4) = *(const float4*)(smem + off);
      }
    }
  }
}

// ---------------- workspace layout (bytes) ----------------
// cnt     @ 0          (512)          — zeroed (with ce) by one memset
// ce      @ 512        (32768)        -> 33280
// ntiles  @ 33280      (4)
// desc    @ 33344      (1088)         -> 34432
// idx     @ 36864      (524288)       -> 561152
// W1p     @ 561152     (16777216)     -> 17338368
// W2p     @ 17338368   (16777216)     -> 34115584
// hp      @ 34115584   (35651584)     -> 69767168  (~69.8 MB; Ap eliminated)

extern "C" void kernel_launch(void* const* d_in, const int* in_sizes, int n_in,
                              void* d_out, int out_size, void* d_ws, size_t ws_size,
                              hipStream_t stream) {
  const float* x   = (const float*)d_in[0];
  const int*   ops = (const int*)d_in[1];
  const float* emb = (const float*)d_in[2];
  const float* W1  = (const float*)d_in[3];
  const float* b1  = (const float*)d_in[4];
  const float* W2  = (const float*)d_in[5];
  const float* b2  = (const float*)d_in[6];
  float* out = (float*)d_out;

  char* ws = (char*)d_ws;
  int* cnt  = (int*)(ws + 0);
  float* ce = (float*)(ws + 512);
  int* ntp  = (int*)(ws + 33280);
  int* desc = (int*)(ws + 33344);
  int* idx  = (int*)(ws + 36864);
  short* W1p = (short*)(ws + 561152);
  short* W2p = (short*)(ws + 17338368);
  unsigned short* hp = (unsigned short*)(ws + 34115584);

  hipMemsetAsync(ws, 0, 33280, stream);   // cnt + ce
  bucket_ce_k<<<192 + 2048, 256, 0, stream>>>(ops, cnt, idx, W1, emb, b1, ce, W1p);
  schedule_k<<<1, 256, 0, stream>>>(cnt, desc, ntp, idx);
  gemm1_w2_k<<<8 * MAXT + 2048, 256, 0, stream>>>(x, idx, ce, W1p, hp, desc, ntp, W2, W2p);
  gemm2_k<<<8 * MAXT, 256, 0, stream>>>(hp, b2, W2p, out, idx, cnt, desc, ntp);
}

// Round 2
// 301.747 us; speedup vs baseline: 1.0751x; 1.0751x over previous
//
#include <hip/hip_runtime.h>
#include <hip/hip_bf16.h>

#define BATCH 16384
#define HID   1024
#define EMBD  512
#define NOPS  8
#define MAXT  136   // max tile slots: sum ceil(cnt_e/128) <= 135
#define CNTS  16    // cnt stride in ints (64 B) — one cache line per expert

typedef __attribute__((ext_vector_type(8))) short bf16x8;
typedef __attribute__((ext_vector_type(4))) float f32x4;

__device__ __forceinline__ unsigned short f2bf(float f) {
  unsigned int u = __float_as_uint(f);
  u += 0x7FFF + ((u >> 16) & 1);
  return (unsigned short)(u >> 16);
}

__device__ __forceinline__ unsigned int pk2(float a, float b) {
  __hip_bfloat162 t = __float22bfloat162_rn(make_float2(a, b));
  return *(unsigned int*)(&t);
}

__device__ __forceinline__ void lds_load16(void* lds, const void* g) {
  __builtin_amdgcn_global_load_lds(
      (const __attribute__((address_space(1))) unsigned int*)g,
      (__attribute__((address_space(3))) unsigned int*)lds, 16, 0, 0);
}

// XCD-locality decode: linear blocks round-robin across 8 XCDs, so bid&7 is
// the XCD. All 8 nx-blocks of a g land on one XCD (A-slab L2 reuse), and each
// XCD covers contiguous g-range [17c, 17c+17) ~= one expert (W-slab in L2).
__device__ __forceinline__ void decode_bid(int bid, int& g, int& nx) {
  g = 17 * (bid & 7) + (bid >> 6);
  nx = (bid >> 3) & 7;
}

// LDS-free weight transpose tile, fq-major slab layout:
//   slab[kq][n][kk] bf16 (kq=k/8 in 0..3, n in 0..127, kk=k%8)
//   value = W[ks*32 + kq*8 + kk][nx*128 + n]
// Fragment ds_read (fq*128+row)*16B hits each bank-quad twice per wave
// (2-way = free, m136) -> conflict-free fragment reads.
__device__ __forceinline__ void w_prep_tile(const float* __restrict__ W,
                                            short* __restrict__ Wp,
                                            int ks, int nx, int tid) {
  int n = tid & 127, kh = tid >> 7;           // kh: low/high 16 of the 32-k tile
  const float* src = W + (size_t)(ks * 32 + kh * 16) * 1024 + nx * 128 + n;
  float v[16];
#pragma unroll
  for (int kk = 0; kk < 16; ++kk) v[kk] = src[(size_t)kk * 1024];
  uint4 a, b;
  a.x = pk2(v[0], v[1]);  a.y = pk2(v[2], v[3]);
  a.z = pk2(v[4], v[5]);  a.w = pk2(v[6], v[7]);
  b.x = pk2(v[8], v[9]);  b.y = pk2(v[10], v[11]);
  b.z = pk2(v[12], v[13]); b.w = pk2(v[14], v[15]);
  uint4* dst = (uint4*)Wp;
  dst[(2 * kh) * 128 + n]     = a;            // kq = 2*kh   (k 0..7 of this half)
  dst[(2 * kh + 1) * 128 + n] = b;            // kq = 2*kh+1 (k 8..15)
}

// ---- phase 0: bucket (64) + ce (128) + W1 prep (2048) + xb convert (4096) ---
// xb = bf16(x) in token order — bucket-independent, so it rides in phase 0.
// gemm1 then gathers A rows straight from xb via per-lane global_load_lds
// (no Ap slab, no prep kernel, no VALU repack on the gemm critical path).
// ce[e][n] = b1[e][n] + sum_k emb[e][k] * W1[e][1024+k][n] — embedding half of
// GEMM1 collapses to a per-(expert,n) constant, cutting GEMM1 K 1536 -> 1024.
__global__ void bucket_ce_k(const int* __restrict__ ops, int* __restrict__ cnt,
                            int* __restrict__ idx, const float* __restrict__ W1,
                            const float* __restrict__ emb,
                            const float* __restrict__ b1, float* __restrict__ ce,
                            short* __restrict__ W1p, const float* __restrict__ x,
                            unsigned int* __restrict__ xb) {
  int bid = blockIdx.x;
  int tid = threadIdx.x;
  if (bid >= 2240) {
    // ---- xb path: f32 -> bf16, 4096 blocks * 4096 elems ----
    size_t i = ((size_t)(bid - 2240) * 256 + tid) * 16;
    const float4* src = (const float4*)(x + i);
    float4 f0 = src[0], f1 = src[1], f2v = src[2], f3 = src[3];
    uint4 p0 = make_uint4(pk2(f0.x, f0.y), pk2(f0.z, f0.w),
                          pk2(f1.x, f1.y), pk2(f1.z, f1.w));
    uint4 p1 = make_uint4(pk2(f2v.x, f2v.y), pk2(f2v.z, f2v.w),
                          pk2(f3.x, f3.y), pk2(f3.z, f3.w));
    uint4* dst = (uint4*)(xb + i / 2);
    dst[0] = p0;
    dst[1] = p1;
    return;
  }
  if (bid >= 192) {
    // ---- W1 path: 8 e * 8 nx * 32 ks (first 1024 rows only) ----
    int b = bid - 192;
    int e = b / 256; int rr = b % 256; int nx = rr / 32, ks = rr % 32;
    w_prep_tile(W1 + (size_t)e * 1536 * 1024,
                W1p + ((size_t)(e * 8 + nx) * 32 + ks) * 4096, ks, nx, tid);
    return;
  }
  if (bid >= 64) {
    // ---- ce path ----
    int cb = bid - 64;
    int e = cb >> 4, kp = cb & 15;
    int n = tid * 4;
    const float* Wc = W1 + (size_t)e * 1536 * 1024 + (size_t)(1024 + kp * 32) * 1024 + n;
    const float* ee = emb + e * EMBD + kp * 32;
    float4 a = make_float4(0.f, 0.f, 0.f, 0.f);
#pragma unroll
    for (int kk = 0; kk < 32; ++kk) {
      float s = ee[kk];
      float4 r = *(const float4*)(Wc + (size_t)kk * 1024);
      a.x += s * r.x; a.y += s * r.y; a.z += s * r.z; a.w += s * r.w;
    }
    if (kp == 0) {
      float4 b = *(const float4*)(b1 + e * HID + n);
      a.x += b.x; a.y += b.y; a.z += b.z; a.w += b.w;
    }
    float* d = ce + e * HID + n;
    atomicAdd(d + 0, a.x); atomicAdd(d + 1, a.y);
    atomicAdd(d + 2, a.z); atomicAdd(d + 3, a.w);
    return;
  }
  // ---- bucket path (block-aggregated atomics) ----
  __shared__ int wcnt[4][NOPS];
  __shared__ int wbase[4][NOPS];
  int lane = tid & 63, w = tid >> 6;
  int t = bid * 256 + tid;
  int op = ops[t];
  unsigned long long msave = 0;
#pragma unroll
  for (int o = 0; o < NOPS; ++o) {
    unsigned long long mm = __ballot(op == o);
    if (op == o) msave = mm;
    if (lane == o) wcnt[w][o] = __popcll(mm);
  }
  __syncthreads();
  if (tid < NOPS) {
    int c0 = wcnt[0][tid], c1 = wcnt[1][tid], c2 = wcnt[2][tid], c3 = wcnt[3][tid];
    int base = atomicAdd(&cnt[tid * CNTS], c0 + c1 + c2 + c3);
    wbase[0][tid] = base;
    wbase[1][tid] = base + c0;
    wbase[2][tid] = base + c0 + c1;
    wbase[3][tid] = base + c0 + c1 + c2;
  }
  __syncthreads();
  int pre = __popcll(msave & ((1ull << lane) - 1ull));
  idx[op * BATCH + wbase[w][op] + pre] = t;
}

// build tile descriptors + pad index lists to tile multiples (parallel fill)
__global__ void schedule_k(const int* __restrict__ cnt, int* __restrict__ desc,
                           int* __restrict__ ntp, int* __restrict__ idx) {
  __shared__ int base[NOPS + 1];
  int tid = threadIdx.x;
  if (tid == 0) {
    int n = 0;
    for (int e = 0; e < NOPS; ++e) { base[e] = n; n += (cnt[e * CNTS] + 127) >> 7; }
    base[NOPS] = n;
    *ntp = n;
  }
  __syncthreads();
  for (int e = 0; e < NOPS; ++e) {
    int b0 = base[e], nt = base[e + 1] - b0;
    for (int t = tid; t < nt; t += 256) {
      desc[2 * (b0 + t)] = e;
      desc[2 * (b0 + t) + 1] = t * 128;
    }
  }
  for (int e = 0; e < NOPS; ++e) {
    int c = cnt[e * CNTS];
    int cp = (c + 127) & ~127;
    for (int p = c + tid; p < cp; p += 256) idx[e * BATCH + p] = 0;
  }
}

// ---------------- phase 1: GEMM1 gathered-DMA A (1088) + W2 prep (2048) ------
// h = relu(x_tile @ W1[e][:1024] + ce[e]); K = 1024 (32 iters).
// A staging: per-lane global_load_lds gather from xb. Wave w covers kq=w; its
// two calls stage rows 0-63 / 64-127 at byte offset ks*64 + w*16 of each
// gathered token row. Token idx + kq are loop-invariant -> per-ks address
// update is one add; zero VALU repack in the loop (round-1 lesson: the fused
// convert+ds_write gather cost 2x, VALUBusy 28%).
// B (W1p) is a linear 8 KB slab copy. W2 prep rides co-resident.
__global__ __launch_bounds__(256) void gemm1_w2_k(
    const unsigned int* __restrict__ xb, const int* __restrict__ idx,
    const float* __restrict__ ce, const short* __restrict__ W1p,
    unsigned short* __restrict__ hp, const int* __restrict__ desc,
    const int* __restrict__ ntp, const float* __restrict__ W2,
    short* __restrict__ W2p) {
  int bid = blockIdx.x;
  int tid = threadIdx.x;
  if (bid >= 8 * MAXT) {
    // ---- W2 path: 8 e * 8 nx * 32 ks ----
    int b = bid - 8 * MAXT;
    int e = b / 256; int rr = b % 256; int nx = rr / 32, ks = rr % 32;
    w_prep_tile(W2 + (size_t)e * 1024 * 1024,
                W2p + ((size_t)(e * 8 + nx) * 32 + ks) * 4096, ks, nx, tid);
    return;
  }
  int g, nx;
  decode_bid(bid, g, nx);
  if (g >= *ntp) return;
  int e = desc[2 * g], rs = desc[2 * g + 1];

  __shared__ __align__(16) char smem[16384];
  short* lA = (short*)smem;
  short* lB = (short*)(smem + 8192);

  int lane = tid & 63, w = tid >> 6;
  int wm = w >> 1, wn = w & 1;
  int fr = lane & 15, fq = lane >> 4;

  // gathered A sources: lane i of wave w stages rows lane / 64+lane, kq=w
  int t0 = idx[e * BATCH + rs + lane];
  int t1 = idx[e * BATCH + rs + 64 + lane];
  const char* a0 = (const char*)xb + (size_t)t0 * 2048 + w * 16;
  const char* a1 = (const char*)xb + (size_t)t1 * 2048 + w * 16;
  const char* Bsrc = (const char*)W1p + (size_t)(e * 8 + nx) * 32 * 8192;

  f32x4 acc[4][4] = {};

  for (int ks = 0; ks < 32; ++ks) {
    const char* bs = Bsrc + ks * 8192;
    lds_load16(smem + w * 2048,        a0 + ks * 64);
    lds_load16(smem + w * 2048 + 1024, a1 + ks * 64);
    lds_load16(smem + 8192 + w * 1024, bs + w * 1024 + lane * 16);
    lds_load16(smem + 12288 + w * 1024, bs + 4096 + w * 1024 + lane * 16);
    __syncthreads();

    bf16x8 af[4], bfr[4];
#pragma unroll
    for (int i = 0; i < 4; ++i)
      af[i] = *(const bf16x8*)&lA[(fq * 128 + wm * 64 + i * 16 + fr) * 8];
#pragma unroll
    for (int j = 0; j < 4; ++j)
      bfr[j] = *(const bf16x8*)&lB[(fq * 128 + wn * 64 + j * 16 + fr) * 8];
#pragma unroll
    for (int i = 0; i < 4; ++i)
#pragma unroll
      for (int j = 0; j < 4; ++j)
        acc[i][j] = __builtin_amdgcn_mfma_f32_16x16x32_bf16(af[i], bfr[j], acc[i][j], 0, 0, 0);
    __syncthreads();
  }

  // epilogue: +ce (bias incl. embedding term) + relu + bf16, coalesced via LDS.
  // hp layout (fq-major): [g][ks2(32)][kq(4)][128 r][8 k] — gemm2 staging is a
  // linear 8 KB slab copy. LDS round-trip gets a 1-bit XOR swizzle.
  float bias[4];
#pragma unroll
  for (int j = 0; j < 4; ++j)
    bias[j] = ce[e * HID + nx * 128 + wn * 64 + j * 16 + fr];

  int lr = lane >> 2;
#pragma unroll
  for (int i = 0; i < 4; ++i) {
    __syncthreads();
#pragma unroll
    for (int j = 0; j < 4; ++j)
#pragma unroll
      for (int rg = 0; rg < 4; ++rg) {
        float v = acc[i][j][rg] + bias[j];
        v = v > 0.f ? v : 0.f;
        int row16 = fq * 4 + rg;
        int off = w * 2048 + row16 * 128 + (j * 16 + fr) * 2;
        off ^= (row16 & 1) << 6;
        *(unsigned short*)(smem + off) = f2bf(v);
      }
    __syncthreads();
    int R = wm * 64 + i * 16 + lr;
#pragma unroll
    for (int s = 0; s < 2; ++s) {
      int ch = (lane & 3) + s * 4;
      int off = w * 2048 + lr * 128 + ch * 16;
      off ^= (lr & 1) << 6;
      uint4 val = *(const uint4*)(smem + off);
      int ks2 = nx * 4 + wn * 2 + (ch >> 2);
      int kq = ch & 3;
      *(uint4*)(hp + (((size_t)(g * 32 + ks2) * 4 + kq) * 128 + R) * 8) = val;
    }
  }
}

// ---------------- phase 2: GEMM2  out[tok] = relu(h @ W2[e] + b2[e]) ---------
__global__ __launch_bounds__(256) void gemm2_k(
    const unsigned short* __restrict__ hp, const float* __restrict__ b2,
    const short* __restrict__ W2p, float* __restrict__ out,
    const int* __restrict__ idx, const int* __restrict__ cnt,
    const int* __restrict__ desc, const int* __restrict__ ntp) {
  int g, nx;
  decode_bid(blockIdx.x, g, nx);
  if (g >= *ntp) return;
  int e = desc[2 * g], rs = desc[2 * g + 1];
  int ce2 = cnt[e * CNTS];

  __shared__ __align__(16) char smem[16384];
  __shared__ int toks[128];
  short* lA = (short*)smem;
  short* lB = (short*)(smem + 8192);

  int tid = threadIdx.x, lane = tid & 63, w = tid >> 6;
  int wm = w >> 1, wn = w & 1;
  int fr = lane & 15, fq = lane >> 4;

  if (tid < 128) toks[tid] = idx[e * BATCH + rs + tid];

  const char* Asrc = (const char*)hp + (size_t)g * 32 * 8192;
  const char* Bsrc = (const char*)W2p + (size_t)(e * 8 + nx) * 32 * 8192;

  f32x4 acc[4][4] = {};

  for (int ks = 0; ks < 32; ++ks) {
    const char* as = Asrc + ks * 8192;
    const char* bs = Bsrc + ks * 8192;
    lds_load16(smem + w * 1024, as + w * 1024 + lane * 16);
    lds_load16(smem + 4096 + w * 1024, as + 4096 + w * 1024 + lane * 16);
    lds_load16(smem + 8192 + w * 1024, bs + w * 1024 + lane * 16);
    lds_load16(smem + 12288 + w * 1024, bs + 4096 + w * 1024 + lane * 16);
    __syncthreads();

    bf16x8 af[4], bfr[4];
#pragma unroll
    for (int i = 0; i < 4; ++i)
      af[i] = *(const bf16x8*)&lA[(fq * 128 + wm * 64 + i * 16 + fr) * 8];
#pragma unroll
    for (int j = 0; j < 4; ++j)
      bfr[j] = *(const bf16x8*)&lB[(fq * 128 + wn * 64 + j * 16 + fr) * 8];
#pragma unroll
    for (int i = 0; i < 4; ++i)
#pragma unroll
      for (int j = 0; j < 4; ++j)
        acc[i][j] = __builtin_amdgcn_mfma_f32_16x16x32_bf16(af[i], bfr[j], acc[i][j], 0, 0, 0);
    __syncthreads();
  }

  // epilogue: bias + relu + scatter to out rows, coalesced via LDS round-trip.
  float bias[4];
#pragma unroll
  for (int j = 0; j < 4; ++j)
    bias[j] = b2[e * HID + nx * 128 + wn * 64 + j * 16 + fr];

  int lr = lane >> 2;
#pragma unroll
  for (int i = 0; i < 4; ++i) {
    __syncthreads();
#pragma unroll
    for (int j = 0; j < 4; ++j)
#pragma unroll
      for (int rg = 0; rg < 4; ++rg) {
        float v = acc[i][j][rg] + bias[j];
        int row16 = fq * 4 + rg;
        int off = w * 4096 + row16 * 256 + (j * 16 + fr) * 4;
        off ^= (row16 & 1) << 6;
        *(float*)(smem + off) = v > 0.f ? v : 0.f;
      }
    __syncthreads();
    int R = wm * 64 + i * 16 + lr;
    if (R < ce2 - rs) {
      float* orow = out + (size_t)toks[R] * HID + nx * 128 + wn * 64;
#pragma unroll
      for (int s = 0; s < 4; ++s) {
        int ch = (lane & 3) + s * 4;
        int off = w * 4096 + lr * 256 + ch * 16;
        off ^= (lr & 1) << 6;
        *(float4*)(orow + ch * 4) = *(const float4*)(smem + off);
      }
    }
  }
}

// ---------------- workspace layout (bytes) ----------------
// cnt     @ 0          (512)          — zeroed (with ce) by one memset
// ce      @ 512        (32768)        -> 33280
// ntiles  @ 33280      (4)
// desc    @ 33344      (1088)         -> 34432
// idx     @ 36864      (524288)       -> 561152
// W1p     @ 561152     (16777216)     -> 17338368
// W2p     @ 17338368   (16777216)     -> 34115584
// hp      @ 34115584   (35651584)     -> 69767168
// xb      @ 69767168   (33554432)     -> 103321600 (~103.3 MB)

extern "C" void kernel_launch(void* const* d_in, const int* in_sizes, int n_in,
                              void* d_out, int out_size, void* d_ws, size_t ws_size,
                              hipStream_t stream) {
  const float* x   = (const float*)d_in[0];
  const int*   ops = (const int*)d_in[1];
  const float* emb = (const float*)d_in[2];
  const float* W1  = (const float*)d_in[3];
  const float* b1  = (const float*)d_in[4];
  const float* W2  = (const float*)d_in[5];
  const float* b2  = (const float*)d_in[6];
  float* out = (float*)d_out;

  char* ws = (char*)d_ws;
  int* cnt  = (int*)(ws + 0);
  float* ce = (float*)(ws + 512);
  int* ntp  = (int*)(ws + 33280);
  int* desc = (int*)(ws + 33344);
  int* idx  = (int*)(ws + 36864);
  short* W1p = (short*)(ws + 561152);
  short* W2p = (short*)(ws + 17338368);
  unsigned short* hp = (unsigned short*)(ws + 34115584);
  unsigned int* xb = (unsigned int*)(ws + 69767168);

  hipMemsetAsync(ws, 0, 33280, stream);   // cnt + ce
  bucket_ce_k<<<2240 + 4096, 256, 0, stream>>>(ops, cnt, idx, W1, emb, b1, ce, W1p, x, xb);
  schedule_k<<<1, 256, 0, stream>>>(cnt, desc, ntp, idx);
  gemm1_w2_k<<<8 * MAXT + 2048, 256, 0, stream>>>(xb, idx, ce, W1p, hp, desc, ntp, W2, W2p);
  gemm2_k<<<8 * MAXT, 256, 0, stream>>>(hp, b2, W2p, out, idx, cnt, desc, ntp);
}